// Round 30
// baseline (155.503 us; speedup 1.0000x reference)
//
#include <hip/hip_runtime.h>

#define NN 100000
#define NE 1600000
#define NT64 1563    // ceil(NN / 64)

#define BSH 7
#define BNODES 128               // nodes per bucket
#define NBUCK 782                // ceil(NN / 128)
#define NBUCKP 784
#define CAP 2560                 // words per bucket region (exp 2048, +11 sigma)
#define ECH 8192                 // edges per chunk
#define NCHK 196                 // ceil(NE / ECH)
#define WFRAG_BLKS 272           // 139264 / 512

typedef _Float16 half8v __attribute__((ext_vector_type(8)));
typedef _Float16 half4v __attribute__((ext_vector_type(4)));
typedef float f32x4 __attribute__((ext_vector_type(4)));

// ---------------- W -> fp16 B-fragment layout ----------------
// Wf[((kt*(N/16)+nt)*64 + l)*8 + j] = W[(kt*32 + (l>>4)*8 + j)*N + nt*16 + (l&15)]

__device__ __forceinline__ void wfrag_one(const float* __restrict__ W,
                                          _Float16* __restrict__ Wf, int idx, int N) {
    int j = idx & 7;
    int l = (idx >> 3) & 63;
    int f = idx >> 9;
    int nt = f % (N / 16);
    int kt = f / (N / 16);
    int k = kt * 32 + (l >> 4) * 8 + j;
    int c = nt * 16 + (l & 15);
    Wf[idx] = (_Float16)W[k * N + c];
}

// ---------------- merged: bucket count (0..195) | wfrag (196..467) ----------------

__global__ __launch_bounds__(512) void k_count_wfrag(const int* __restrict__ dst,
                                                     int* __restrict__ histT,
                                                     const float* __restrict__ W1,
                                                     const float* __restrict__ W2,
                                                     const float* __restrict__ W3,
                                                     _Float16* __restrict__ Wf1,
                                                     _Float16* __restrict__ Wf2,
                                                     _Float16* __restrict__ Wf3) {
    const int t = threadIdx.x;
    if (blockIdx.x >= NCHK) {
        int idx = (blockIdx.x - NCHK) * 512 + t;
        if (idx < 65536) wfrag_one(W1, Wf1, idx, 256);
        else if (idx < 131072) wfrag_one(W2, Wf2, idx - 65536, 256);
        else if (idx < 139264) wfrag_one(W3, Wf3, idx - 131072, 32);
        return;
    }
    __shared__ int h[NBUCKP];
    const int blk = blockIdx.x;
    for (int b = t; b < NBUCKP; b += 512) h[b] = 0;
    __syncthreads();
    const int ebase = blk * ECH + t * 16;
#pragma unroll
    for (int q = 0; q < 4; q++) {
        int e = ebase + q * 4;
        if (e + 4 <= NE) {
            int4 d4 = *reinterpret_cast<const int4*>(dst + e);
            atomicAdd(&h[d4.x >> BSH], 1);
            atomicAdd(&h[d4.y >> BSH], 1);
            atomicAdd(&h[d4.z >> BSH], 1);
            atomicAdd(&h[d4.w >> BSH], 1);
        } else {
            for (int p = e; p < NE; p++) atomicAdd(&h[dst[p] >> BSH], 1);
            break;
        }
    }
    __syncthreads();
    for (int b = t; b < NBUCK; b += 512) histT[(long long)b * NCHK + blk] = h[b];
}

// ---------------- per-bucket exclusive scan over chunks ----------------

__global__ __launch_bounds__(256) void k_scanb(int* __restrict__ histT,
                                               int* __restrict__ cntb) {
    __shared__ int s[256];
    const int b = blockIdx.x, t = threadIdx.x;
    int* row = histT + (long long)b * NCHK;
    int v = (t < NCHK) ? row[t] : 0;
    s[t] = v;
    __syncthreads();
    for (int off = 1; off < 256; off <<= 1) {
        int u = (t >= off) ? s[t - off] : 0;
        __syncthreads();
        s[t] += u;
        __syncthreads();
    }
    if (t < NCHK) row[t] = s[t] - v;
    if (t == 255) cntb[b] = s[255];
}

// ---------------- merged: part scatter (0..195) | fused MLP (196..1758) ----------------

__global__ __launch_bounds__(512) void k_part_mlp(const int* __restrict__ src,
                                                  const int* __restrict__ dst,
                                                  const int* __restrict__ histT,
                                                  int* __restrict__ data,
                                                  const float* __restrict__ x,
                                                  const _Float16* __restrict__ Wf1,
                                                  const _Float16* __restrict__ Wf2,
                                                  const _Float16* __restrict__ Wf3,
                                                  const float* __restrict__ b1,
                                                  const float* __restrict__ b2,
                                                  const float* __restrict__ b3,
                                                  _Float16* __restrict__ h0f) {
    __shared__ char smem[32768];
    const int t = threadIdx.x;

    if (blockIdx.x < NCHK) {
        // ---- bucket partition scatter ----
        int* curs = (int*)smem;
        const int blk = blockIdx.x;
        for (int b = t; b < NBUCKP; b += 512)
            curs[b] = b * CAP + ((b < NBUCK) ? histT[(long long)b * NCHK + blk] : 0);
        __syncthreads();
        const int ebase = blk * ECH + t * 16;
#pragma unroll
        for (int q = 0; q < 4; q++) {
            int e = ebase + q * 4;
            if (e + 4 <= NE) {
                int4 d4 = *reinterpret_cast<const int4*>(dst + e);
                int4 s4 = *reinterpret_cast<const int4*>(src + e);
                int p0 = atomicAdd(&curs[d4.x >> BSH], 1);
                data[p0] = (s4.x << BSH) | (d4.x & (BNODES - 1));
                int p1 = atomicAdd(&curs[d4.y >> BSH], 1);
                data[p1] = (s4.y << BSH) | (d4.y & (BNODES - 1));
                int p2 = atomicAdd(&curs[d4.z >> BSH], 1);
                data[p2] = (s4.z << BSH) | (d4.z & (BNODES - 1));
                int p3 = atomicAdd(&curs[d4.w >> BSH], 1);
                data[p3] = (s4.w << BSH) | (d4.w & (BNODES - 1));
            } else {
                for (int p = e; p < NE; p++) {
                    int d = dst[p], sv = src[p];
                    int pos = atomicAdd(&curs[d >> BSH], 1);
                    data[pos] = (sv << BSH) | (d & (BNODES - 1));
                }
                break;
            }
        }
        return;
    }

    // ---- fused MLP: 64 rows/block, single 32KB buffer ----
    char* buf = smem;
    const int lane = t & 63;
    const int G = lane >> 4;
    const int w = t >> 6;
    const int T = blockIdx.x - NCHK;
    const long long row0 = (long long)T * 64;

    const half8v* W1f = reinterpret_cast<const half8v*>(Wf1);
    const half8v* W2f = reinterpret_cast<const half8v*>(Wf2);
    float bv1[2], bv2[2];
#pragma unroll
    for (int n2 = 0; n2 < 2; n2++) {
        bv1[n2] = b1[w * 32 + n2 * 16 + (lane & 15)];
        bv2[n2] = b2[w * 32 + n2 * 16 + (lane & 15)];
    }

    // stage x tile fp32 -> fp16 swizzled (issue loads first)
    {
        const float4* A4 = reinterpret_cast<const float4*>(x + row0 * 256);
        float4 v[8];
#pragma unroll
        for (int q = 0; q < 8; q++) {
            int i = t + q * 512;
            int r = i >> 6;
            v[q] = make_float4(0.f, 0.f, 0.f, 0.f);
            if (row0 + r < NN) v[q] = A4[i];
        }
        __builtin_amdgcn_sched_barrier(0);
#pragma unroll
        for (int q = 0; q < 8; q++) {
            int i = t + q * 512;
            int r = i >> 6, c4 = i & 63;
            half4v hv;
            hv[0] = (_Float16)v[q].x; hv[1] = (_Float16)v[q].y;
            hv[2] = (_Float16)v[q].z; hv[3] = (_Float16)v[q].w;
            int bo = (r * 512 + c4 * 8) ^ ((r & 7) << 4);
            *reinterpret_cast<half4v*>(buf + bo) = hv;
        }
    }
    __syncthreads();

    f32x4 acc[4][2];

    // GEMM1
#pragma unroll
    for (int mt = 0; mt < 4; mt++)
#pragma unroll
        for (int n2 = 0; n2 < 2; n2++) acc[mt][n2] = (f32x4)0.f;
#pragma unroll
    for (int kt = 0; kt < 8; kt++) {
        half8v a[4], bfr[2];
#pragma unroll
        for (int n2 = 0; n2 < 2; n2++)
            bfr[n2] = W1f[(kt * 16 + 2 * w + n2) * 64 + lane];
#pragma unroll
        for (int mt = 0; mt < 4; mt++) {
            int row = mt * 16 + (lane & 15);
            int bo = (row * 512 + kt * 64 + (G << 4)) ^ ((row & 7) << 4);
            a[mt] = *reinterpret_cast<const half8v*>(buf + bo);
        }
#pragma unroll
        for (int mt = 0; mt < 4; mt++)
#pragma unroll
            for (int n2 = 0; n2 < 2; n2++)
                acc[mt][n2] = __builtin_amdgcn_mfma_f32_16x16x32_f16(a[mt], bfr[n2], acc[mt][n2], 0, 0, 0);
    }
    __syncthreads();

    // h1 = relu(acc + b1) -> LDS in place
#pragma unroll
    for (int mt = 0; mt < 4; mt++)
#pragma unroll
        for (int n2 = 0; n2 < 2; n2++) {
            int colc = w * 32 + n2 * 16 + (lane & 15);
            float bb = bv1[n2];
#pragma unroll
            for (int r = 0; r < 4; r++) {
                int row = mt * 16 + G * 4 + r;
                float v = fmaxf(acc[mt][n2][r] + bb, 0.f);
                int bo = (row * 512 + colc * 2) ^ ((row & 7) << 4);
                *reinterpret_cast<_Float16*>(buf + bo) = (_Float16)v;
            }
        }
    __syncthreads();

    // GEMM2
#pragma unroll
    for (int mt = 0; mt < 4; mt++)
#pragma unroll
        for (int n2 = 0; n2 < 2; n2++) acc[mt][n2] = (f32x4)0.f;
#pragma unroll
    for (int kt = 0; kt < 8; kt++) {
        half8v a[4], bfr[2];
#pragma unroll
        for (int n2 = 0; n2 < 2; n2++)
            bfr[n2] = W2f[(kt * 16 + 2 * w + n2) * 64 + lane];
#pragma unroll
        for (int mt = 0; mt < 4; mt++) {
            int row = mt * 16 + (lane & 15);
            int bo = (row * 512 + kt * 64 + (G << 4)) ^ ((row & 7) << 4);
            a[mt] = *reinterpret_cast<const half8v*>(buf + bo);
        }
#pragma unroll
        for (int mt = 0; mt < 4; mt++)
#pragma unroll
            for (int n2 = 0; n2 < 2; n2++)
                acc[mt][n2] = __builtin_amdgcn_mfma_f32_16x16x32_f16(a[mt], bfr[n2], acc[mt][n2], 0, 0, 0);
    }
    __syncthreads();

    // h2 = relu(acc + b2) -> LDS in place
#pragma unroll
    for (int mt = 0; mt < 4; mt++)
#pragma unroll
        for (int n2 = 0; n2 < 2; n2++) {
            int colc = w * 32 + n2 * 16 + (lane & 15);
            float bb = bv2[n2];
#pragma unroll
            for (int r = 0; r < 4; r++) {
                int row = mt * 16 + G * 4 + r;
                float v = fmaxf(acc[mt][n2][r] + bb, 0.f);
                int bo = (row * 512 + colc * 2) ^ ((row & 7) << 4);
                *reinterpret_cast<_Float16*>(buf + bo) = (_Float16)v;
            }
        }
    __syncthreads();

    // GEMM3: 8 16x16 tiles, one per wave -> h0f only
    {
        const half8v* W3f = reinterpret_cast<const half8v*>(Wf3);
        const int mt3 = w >> 1, ct3 = w & 1;
        const float bb3 = b3[ct3 * 16 + (lane & 15)];
        f32x4 a3 = (f32x4)0.f;
#pragma unroll
        for (int kt = 0; kt < 8; kt++) {
            int row = mt3 * 16 + (lane & 15);
            int bo = (row * 512 + kt * 64 + (G << 4)) ^ ((row & 7) << 4);
            half8v a = *reinterpret_cast<const half8v*>(buf + bo);
            half8v b = W3f[(kt * 2 + ct3) * 64 + lane];
            a3 = __builtin_amdgcn_mfma_f32_16x16x32_f16(a, b, a3, 0, 0, 0);
        }
        int colc = ct3 * 16 + (lane & 15);
#pragma unroll
        for (int r = 0; r < 4; r++) {
            long long row = row0 + mt3 * 16 + G * 4 + r;
            if (row < NN) h0f[row * 32 + colc] = (_Float16)(a3[r] + bb3);
        }
    }
}

// ---------------- per-bucket LDS counting sort -> CSR + dinv (512 threads) ----------------

__global__ __launch_bounds__(512) void k_sortb(const int* __restrict__ data,
                                               const int* __restrict__ cntb,
                                               int* __restrict__ col,
                                               int* __restrict__ begp,
                                               int* __restrict__ endp,
                                               float* __restrict__ dinv) {
    __shared__ int hist[BNODES];
    __shared__ int scn[BNODES];
    __shared__ int curs[BNODES];
    const int b = blockIdx.x, t = threadIdx.x;
    if (t < BNODES) hist[t] = 0;
    __syncthreads();
    const int cnt = cntb[b];
    const int* wp = data + b * CAP;
    for (int e = t; e < cnt; e += 512) atomicAdd(&hist[wp[e] & (BNODES - 1)], 1);
    __syncthreads();
    if (t < BNODES) scn[t] = hist[t];
    __syncthreads();
    for (int off = 1; off < BNODES; off <<= 1) {
        int v = (t < BNODES && t >= off) ? scn[t - off] : 0;
        __syncthreads();
        if (t < BNODES) scn[t] += v;
        __syncthreads();
    }
    if (t < BNODES) {
        int beg = scn[t] - hist[t];
        curs[t] = beg;
        int node = (b << BSH) + t;
        if (node < NN) {
            begp[node] = b * CAP + beg;
            endp[node] = b * CAP + scn[t];
            dinv[node] = rsqrtf((float)(hist[t] + 1));
        }
    }
    __syncthreads();
    for (int e = t; e < cnt; e += 512) {
        int w = wp[e];
        int p = atomicAdd(&curs[w & (BNODES - 1)], 1);
        col[b * CAP + p] = w >> BSH;
    }
}

// ---------------- fused APPNP step (512 thr, 8 nodes/block; folded dinv iter 1) ----------------
// FINAL=false: hs = h0f unscaled; gather applies dinv[s]; writes hs1 = f16(dd*hnew).
// FINAL=true : hs prescaled; writes fp32 out.

template<bool FINAL>
__global__ __launch_bounds__(512) void k_appnp(const int* __restrict__ begp,
                                               const int* __restrict__ endp,
                                               const int* __restrict__ col,
                                               const float* __restrict__ dinv,
                                               const _Float16* __restrict__ hs,
                                               const _Float16* __restrict__ h0f,
                                               void* __restrict__ outp) {
    int node = blockIdx.x * 8 + (threadIdx.x >> 6);
    if (node >= NN) return;
    const int lane = threadIdx.x & 63;
    const int slot = lane >> 2;
    const int cg = lane & 3;

    const int beg = begp[node];
    const int end = endp[node];
    const float dd = dinv[node];
    const half8v selfv = *reinterpret_cast<const half8v*>(hs + (size_t)node * 32 + cg * 8);

    float acc[8];
#pragma unroll
    for (int j = 0; j < 8; j++) acc[j] = 0.f;

    for (int e = beg + slot; e < end; e += 16) {
        int s = col[e];
        half8v v = *reinterpret_cast<const half8v*>(hs + (size_t)s * 32 + cg * 8);
        float sc = 1.f;
        if (!FINAL) sc = dinv[s];
#pragma unroll
        for (int j = 0; j < 8; j++) acc[j] += sc * (float)v[j];
    }

#pragma unroll
    for (int off = 4; off < 64; off <<= 1) {
#pragma unroll
        for (int j = 0; j < 8; j++) acc[j] += __shfl_xor(acc[j], off, 64);
    }

    if (slot == 0) {
        size_t off = (size_t)node * 32 + cg * 8;
        if (FINAL) {
            const half8v h0v = *reinterpret_cast<const half8v*>(h0f + off);
            float o[8];
#pragma unroll
            for (int j = 0; j < 8; j++)
                o[j] = 0.9f * dd * (acc[j] + (float)selfv[j]) + 0.1f * (float)h0v[j];
            float4 v0 = make_float4(o[0], o[1], o[2], o[3]);
            float4 v1 = make_float4(o[4], o[5], o[6], o[7]);
            float4* op = reinterpret_cast<float4*>((float*)outp + off);
            op[0] = v0; op[1] = v1;
        } else {
            half8v hv;
#pragma unroll
            for (int j = 0; j < 8; j++) {
                float sv = (float)selfv[j];
                float hnew = 0.9f * dd * (acc[j] + dd * sv) + 0.1f * sv;
                hv[j] = (_Float16)(dd * hnew);
            }
            *reinterpret_cast<half8v*>((_Float16*)outp + off) = hv;
        }
    }
}

// ---------------- launch ----------------

extern "C" void kernel_launch(void* const* d_in, const int* in_sizes, int n_in,
                              void* d_out, int out_size, void* d_ws, size_t ws_size,
                              hipStream_t stream) {
    const float* x     = (const float*)d_in[0];
    const int*   ei    = (const int*)d_in[1];
    const float* W_in  = (const float*)d_in[2];
    const float* b_in  = (const float*)d_in[3];
    const float* W_h   = (const float*)d_in[4];
    const float* b_h   = (const float*)d_in[5];
    const float* W_out = (const float*)d_in[6];
    const float* b_out = (const float*)d_in[7];
    float* out = (float*)d_out;

    const int* srcv = ei;
    const int* dstv = ei + NE;

    char* ws = (char*)d_ws;
    _Float16* h0f  = (_Float16*)ws;                              // NN*32 f16
    _Float16* hs1  = h0f + (size_t)NN * 32;                      // NN*32 f16
    float* dinv    = (float*)(hs1 + (size_t)NN * 32);            // NN
    _Float16* Wf_in  = (_Float16*)(dinv + NN);                   // 256*256
    _Float16* Wf_h   = Wf_in + 256 * 256;                        // 256*256
    _Float16* Wf_out = Wf_h + 256 * 256;                         // 256*32
    int* histT = (int*)(Wf_out + 256 * 32);                      // NBUCK*NCHK
    int* cntb  = histT + (size_t)NBUCK * NCHK;                   // NBUCKP
    int* data  = cntb + NBUCKP;                                  // NBUCKP*CAP
    int* col   = data + (size_t)NBUCKP * CAP;                    // NBUCKP*CAP
    int* begp  = col + (size_t)NBUCKP * CAP;                     // NN
    int* endp  = begp + NN;                                      // NN

    // --- [bucket count | W fragments] ---
    k_count_wfrag<<<NCHK + WFRAG_BLKS, 512, 0, stream>>>(dstv, histT,
                                                         W_in, W_h, W_out,
                                                         Wf_in, Wf_h, Wf_out);
    // --- per-bucket scan ---
    k_scanb<<<NBUCK, 256, 0, stream>>>(histT, cntb);

    // --- [part scatter | fused MLP (inline conversion, h0f only)] ---
    k_part_mlp<<<NCHK + NT64, 512, 0, stream>>>(srcv, dstv, histT, data,
                                                x, Wf_in, Wf_h, Wf_out,
                                                b_in, b_h, b_out, h0f);

    // --- per-bucket counting sort -> CSR + dinv ---
    k_sortb<<<NBUCK, 512, 0, stream>>>(data, cntb, col, begp, endp, dinv);

    // --- APPNP: K = 2 (iter1 folds dinv; iter2 prescaled) ---
    k_appnp<false><<<(NN + 7) / 8, 512, 0, stream>>>(begp, endp, col, dinv, h0f, h0f, hs1);
    k_appnp<true ><<<(NN + 7) / 8, 512, 0, stream>>>(begp, endp, col, dinv, hs1, h0f, out);
}

// Round 31
// 153.095 us; speedup vs baseline: 1.0157x; 1.0157x over previous
//
#include <hip/hip_runtime.h>

#define NN 100000
#define NE 1600000
#define NT64 1563    // ceil(NN / 64)

#define BSH 7
#define BNODES 128               // nodes per bucket
#define NBUCK 782                // ceil(NN / 128)
#define NBUCKP 784
#define CAP 2560                 // words per bucket region (exp 2048, +11 sigma)
#define ECH 8192                 // edges per chunk
#define NCHK 196                 // ceil(NE / ECH)
#define WFRAG_BLKS 272           // 139264 / 512

typedef _Float16 half8v __attribute__((ext_vector_type(8)));
typedef _Float16 half4v __attribute__((ext_vector_type(4)));
typedef float f32x4 __attribute__((ext_vector_type(4)));

// ---------------- W -> fp16 B-fragment layout ----------------
// Wf[((kt*(N/16)+nt)*64 + l)*8 + j] = W[(kt*32 + (l>>4)*8 + j)*N + nt*16 + (l&15)]

__device__ __forceinline__ void wfrag_one(const float* __restrict__ W,
                                          _Float16* __restrict__ Wf, int idx, int N) {
    int j = idx & 7;
    int l = (idx >> 3) & 63;
    int f = idx >> 9;
    int nt = f % (N / 16);
    int kt = f / (N / 16);
    int k = kt * 32 + (l >> 4) * 8 + j;
    int c = nt * 16 + (l & 15);
    Wf[idx] = (_Float16)W[k * N + c];
}

// ---------------- merged: bucket count (0..195) | wfrag (196..467) ----------------

__global__ __launch_bounds__(512) void k_count_wfrag(const int* __restrict__ dst,
                                                     int* __restrict__ histT,
                                                     const float* __restrict__ W1,
                                                     const float* __restrict__ W2,
                                                     const float* __restrict__ W3,
                                                     _Float16* __restrict__ Wf1,
                                                     _Float16* __restrict__ Wf2,
                                                     _Float16* __restrict__ Wf3) {
    const int t = threadIdx.x;
    if (blockIdx.x >= NCHK) {
        int idx = (blockIdx.x - NCHK) * 512 + t;
        if (idx < 65536) wfrag_one(W1, Wf1, idx, 256);
        else if (idx < 131072) wfrag_one(W2, Wf2, idx - 65536, 256);
        else if (idx < 139264) wfrag_one(W3, Wf3, idx - 131072, 32);
        return;
    }
    __shared__ int h[NBUCKP];
    const int blk = blockIdx.x;
    for (int b = t; b < NBUCKP; b += 512) h[b] = 0;
    __syncthreads();
    const int ebase = blk * ECH + t * 16;
#pragma unroll
    for (int q = 0; q < 4; q++) {
        int e = ebase + q * 4;
        if (e + 4 <= NE) {
            int4 d4 = *reinterpret_cast<const int4*>(dst + e);
            atomicAdd(&h[d4.x >> BSH], 1);
            atomicAdd(&h[d4.y >> BSH], 1);
            atomicAdd(&h[d4.z >> BSH], 1);
            atomicAdd(&h[d4.w >> BSH], 1);
        } else {
            for (int p = e; p < NE; p++) atomicAdd(&h[dst[p] >> BSH], 1);
            break;
        }
    }
    __syncthreads();
    for (int b = t; b < NBUCK; b += 512) histT[(long long)b * NCHK + blk] = h[b];
}

// ---------------- per-bucket exclusive scan over chunks ----------------

__global__ __launch_bounds__(256) void k_scanb(int* __restrict__ histT,
                                               int* __restrict__ cntb) {
    __shared__ int s[256];
    const int b = blockIdx.x, t = threadIdx.x;
    int* row = histT + (long long)b * NCHK;
    int v = (t < NCHK) ? row[t] : 0;
    s[t] = v;
    __syncthreads();
    for (int off = 1; off < 256; off <<= 1) {
        int u = (t >= off) ? s[t - off] : 0;
        __syncthreads();
        s[t] += u;
        __syncthreads();
    }
    if (t < NCHK) row[t] = s[t] - v;
    if (t == 255) cntb[b] = s[255];
}

// ---------------- merged: part scatter (0..195) | fused MLP (196..1758) ----------------

__global__ __launch_bounds__(512) void k_part_mlp(const int* __restrict__ src,
                                                  const int* __restrict__ dst,
                                                  const int* __restrict__ histT,
                                                  int* __restrict__ data,
                                                  const float* __restrict__ x,
                                                  const _Float16* __restrict__ Wf1,
                                                  const _Float16* __restrict__ Wf2,
                                                  const _Float16* __restrict__ Wf3,
                                                  const float* __restrict__ b1,
                                                  const float* __restrict__ b2,
                                                  const float* __restrict__ b3,
                                                  _Float16* __restrict__ h0f) {
    __shared__ char smem[32768];
    const int t = threadIdx.x;

    if (blockIdx.x < NCHK) {
        // ---- bucket partition scatter ----
        int* curs = (int*)smem;
        const int blk = blockIdx.x;
        for (int b = t; b < NBUCKP; b += 512)
            curs[b] = b * CAP + ((b < NBUCK) ? histT[(long long)b * NCHK + blk] : 0);
        __syncthreads();
        const int ebase = blk * ECH + t * 16;
#pragma unroll
        for (int q = 0; q < 4; q++) {
            int e = ebase + q * 4;
            if (e + 4 <= NE) {
                int4 d4 = *reinterpret_cast<const int4*>(dst + e);
                int4 s4 = *reinterpret_cast<const int4*>(src + e);
                int p0 = atomicAdd(&curs[d4.x >> BSH], 1);
                data[p0] = (s4.x << BSH) | (d4.x & (BNODES - 1));
                int p1 = atomicAdd(&curs[d4.y >> BSH], 1);
                data[p1] = (s4.y << BSH) | (d4.y & (BNODES - 1));
                int p2 = atomicAdd(&curs[d4.z >> BSH], 1);
                data[p2] = (s4.z << BSH) | (d4.z & (BNODES - 1));
                int p3 = atomicAdd(&curs[d4.w >> BSH], 1);
                data[p3] = (s4.w << BSH) | (d4.w & (BNODES - 1));
            } else {
                for (int p = e; p < NE; p++) {
                    int d = dst[p], sv = src[p];
                    int pos = atomicAdd(&curs[d >> BSH], 1);
                    data[pos] = (sv << BSH) | (d & (BNODES - 1));
                }
                break;
            }
        }
        return;
    }

    // ---- fused MLP: 64 rows/block, single 32KB buffer ----
    char* buf = smem;
    const int lane = t & 63;
    const int G = lane >> 4;
    const int w = t >> 6;
    const int T = blockIdx.x - NCHK;
    const long long row0 = (long long)T * 64;

    const half8v* W1f = reinterpret_cast<const half8v*>(Wf1);
    const half8v* W2f = reinterpret_cast<const half8v*>(Wf2);
    float bv1[2], bv2[2];
#pragma unroll
    for (int n2 = 0; n2 < 2; n2++) {
        bv1[n2] = b1[w * 32 + n2 * 16 + (lane & 15)];
        bv2[n2] = b2[w * 32 + n2 * 16 + (lane & 15)];
    }

    // stage x tile fp32 -> fp16 swizzled (issue loads first)
    {
        const float4* A4 = reinterpret_cast<const float4*>(x + row0 * 256);
        float4 v[8];
#pragma unroll
        for (int q = 0; q < 8; q++) {
            int i = t + q * 512;
            int r = i >> 6;
            v[q] = make_float4(0.f, 0.f, 0.f, 0.f);
            if (row0 + r < NN) v[q] = A4[i];
        }
        __builtin_amdgcn_sched_barrier(0);
#pragma unroll
        for (int q = 0; q < 8; q++) {
            int i = t + q * 512;
            int r = i >> 6, c4 = i & 63;
            half4v hv;
            hv[0] = (_Float16)v[q].x; hv[1] = (_Float16)v[q].y;
            hv[2] = (_Float16)v[q].z; hv[3] = (_Float16)v[q].w;
            int bo = (r * 512 + c4 * 8) ^ ((r & 7) << 4);
            *reinterpret_cast<half4v*>(buf + bo) = hv;
        }
    }
    __syncthreads();

    f32x4 acc[4][2];

    // GEMM1
#pragma unroll
    for (int mt = 0; mt < 4; mt++)
#pragma unroll
        for (int n2 = 0; n2 < 2; n2++) acc[mt][n2] = (f32x4)0.f;
#pragma unroll
    for (int kt = 0; kt < 8; kt++) {
        half8v a[4], bfr[2];
#pragma unroll
        for (int n2 = 0; n2 < 2; n2++)
            bfr[n2] = W1f[(kt * 16 + 2 * w + n2) * 64 + lane];
#pragma unroll
        for (int mt = 0; mt < 4; mt++) {
            int row = mt * 16 + (lane & 15);
            int bo = (row * 512 + kt * 64 + (G << 4)) ^ ((row & 7) << 4);
            a[mt] = *reinterpret_cast<const half8v*>(buf + bo);
        }
#pragma unroll
        for (int mt = 0; mt < 4; mt++)
#pragma unroll
            for (int n2 = 0; n2 < 2; n2++)
                acc[mt][n2] = __builtin_amdgcn_mfma_f32_16x16x32_f16(a[mt], bfr[n2], acc[mt][n2], 0, 0, 0);
    }
    __syncthreads();

    // h1 = relu(acc + b1) -> LDS in place
#pragma unroll
    for (int mt = 0; mt < 4; mt++)
#pragma unroll
        for (int n2 = 0; n2 < 2; n2++) {
            int colc = w * 32 + n2 * 16 + (lane & 15);
            float bb = bv1[n2];
#pragma unroll
            for (int r = 0; r < 4; r++) {
                int row = mt * 16 + G * 4 + r;
                float v = fmaxf(acc[mt][n2][r] + bb, 0.f);
                int bo = (row * 512 + colc * 2) ^ ((row & 7) << 4);
                *reinterpret_cast<_Float16*>(buf + bo) = (_Float16)v;
            }
        }
    __syncthreads();

    // GEMM2
#pragma unroll
    for (int mt = 0; mt < 4; mt++)
#pragma unroll
        for (int n2 = 0; n2 < 2; n2++) acc[mt][n2] = (f32x4)0.f;
#pragma unroll
    for (int kt = 0; kt < 8; kt++) {
        half8v a[4], bfr[2];
#pragma unroll
        for (int n2 = 0; n2 < 2; n2++)
            bfr[n2] = W2f[(kt * 16 + 2 * w + n2) * 64 + lane];
#pragma unroll
        for (int mt = 0; mt < 4; mt++) {
            int row = mt * 16 + (lane & 15);
            int bo = (row * 512 + kt * 64 + (G << 4)) ^ ((row & 7) << 4);
            a[mt] = *reinterpret_cast<const half8v*>(buf + bo);
        }
#pragma unroll
        for (int mt = 0; mt < 4; mt++)
#pragma unroll
            for (int n2 = 0; n2 < 2; n2++)
                acc[mt][n2] = __builtin_amdgcn_mfma_f32_16x16x32_f16(a[mt], bfr[n2], acc[mt][n2], 0, 0, 0);
    }
    __syncthreads();

    // h2 = relu(acc + b2) -> LDS in place
#pragma unroll
    for (int mt = 0; mt < 4; mt++)
#pragma unroll
        for (int n2 = 0; n2 < 2; n2++) {
            int colc = w * 32 + n2 * 16 + (lane & 15);
            float bb = bv2[n2];
#pragma unroll
            for (int r = 0; r < 4; r++) {
                int row = mt * 16 + G * 4 + r;
                float v = fmaxf(acc[mt][n2][r] + bb, 0.f);
                int bo = (row * 512 + colc * 2) ^ ((row & 7) << 4);
                *reinterpret_cast<_Float16*>(buf + bo) = (_Float16)v;
            }
        }
    __syncthreads();

    // GEMM3: 8 16x16 tiles, one per wave -> h0f only
    {
        const half8v* W3f = reinterpret_cast<const half8v*>(Wf3);
        const int mt3 = w >> 1, ct3 = w & 1;
        const float bb3 = b3[ct3 * 16 + (lane & 15)];
        f32x4 a3 = (f32x4)0.f;
#pragma unroll
        for (int kt = 0; kt < 8; kt++) {
            int row = mt3 * 16 + (lane & 15);
            int bo = (row * 512 + kt * 64 + (G << 4)) ^ ((row & 7) << 4);
            half8v a = *reinterpret_cast<const half8v*>(buf + bo);
            half8v b = W3f[(kt * 2 + ct3) * 64 + lane];
            a3 = __builtin_amdgcn_mfma_f32_16x16x32_f16(a, b, a3, 0, 0, 0);
        }
        int colc = ct3 * 16 + (lane & 15);
#pragma unroll
        for (int r = 0; r < 4; r++) {
            long long row = row0 + mt3 * 16 + G * 4 + r;
            if (row < NN) h0f[row * 32 + colc] = (_Float16)(a3[r] + bb3);
        }
    }
}

// ---------------- per-bucket LDS counting sort -> CSR + dinv ----------------

__global__ __launch_bounds__(256) void k_sortb(const int* __restrict__ data,
                                               const int* __restrict__ cntb,
                                               int* __restrict__ col,
                                               int* __restrict__ begp,
                                               int* __restrict__ endp,
                                               float* __restrict__ dinv) {
    __shared__ int hist[BNODES];
    __shared__ int scn[BNODES];
    __shared__ int curs[BNODES];
    const int b = blockIdx.x, t = threadIdx.x;
    if (t < BNODES) hist[t] = 0;
    __syncthreads();
    const int cnt = cntb[b];
    const int* wp = data + b * CAP;
    for (int e = t; e < cnt; e += 256) atomicAdd(&hist[wp[e] & (BNODES - 1)], 1);
    __syncthreads();
    if (t < BNODES) scn[t] = hist[t];
    __syncthreads();
    for (int off = 1; off < BNODES; off <<= 1) {
        int v = (t < BNODES && t >= off) ? scn[t - off] : 0;
        __syncthreads();
        if (t < BNODES) scn[t] += v;
        __syncthreads();
    }
    if (t < BNODES) {
        int beg = scn[t] - hist[t];
        curs[t] = beg;
        int node = (b << BSH) + t;
        if (node < NN) {
            begp[node] = b * CAP + beg;
            endp[node] = b * CAP + scn[t];
            dinv[node] = rsqrtf((float)(hist[t] + 1));
        }
    }
    __syncthreads();
    for (int e = t; e < cnt; e += 256) {
        int w = wp[e];
        int p = atomicAdd(&curs[w & (BNODES - 1)], 1);
        col[b * CAP + p] = w >> BSH;
    }
}

// ---------------- fused APPNP step (folded dinv on iter 1; verified) ----------------
// FINAL=false: hs = h0f unscaled; gather applies dinv[s]; writes hs1 = f16(dd*hnew).
// FINAL=true : hs prescaled; writes fp32 out.

template<bool FINAL>
__global__ __launch_bounds__(256) void k_appnp(const int* __restrict__ begp,
                                               const int* __restrict__ endp,
                                               const int* __restrict__ col,
                                               const float* __restrict__ dinv,
                                               const _Float16* __restrict__ hs,
                                               const _Float16* __restrict__ h0f,
                                               void* __restrict__ outp) {
    int node = blockIdx.x * 4 + (threadIdx.x >> 6);
    if (node >= NN) return;
    const int lane = threadIdx.x & 63;
    const int slot = lane >> 2;
    const int cg = lane & 3;

    const int beg = begp[node];
    const int end = endp[node];
    const float dd = dinv[node];
    const half8v selfv = *reinterpret_cast<const half8v*>(hs + (size_t)node * 32 + cg * 8);

    float acc[8];
#pragma unroll
    for (int j = 0; j < 8; j++) acc[j] = 0.f;

    for (int e = beg + slot; e < end; e += 16) {
        int s = col[e];
        half8v v = *reinterpret_cast<const half8v*>(hs + (size_t)s * 32 + cg * 8);
        float sc = 1.f;
        if (!FINAL) sc = dinv[s];
#pragma unroll
        for (int j = 0; j < 8; j++) acc[j] += sc * (float)v[j];
    }

#pragma unroll
    for (int off = 4; off < 64; off <<= 1) {
#pragma unroll
        for (int j = 0; j < 8; j++) acc[j] += __shfl_xor(acc[j], off, 64);
    }

    if (slot == 0) {
        size_t off = (size_t)node * 32 + cg * 8;
        if (FINAL) {
            const half8v h0v = *reinterpret_cast<const half8v*>(h0f + off);
            float o[8];
#pragma unroll
            for (int j = 0; j < 8; j++)
                o[j] = 0.9f * dd * (acc[j] + (float)selfv[j]) + 0.1f * (float)h0v[j];
            float4 v0 = make_float4(o[0], o[1], o[2], o[3]);
            float4 v1 = make_float4(o[4], o[5], o[6], o[7]);
            float4* op = reinterpret_cast<float4*>((float*)outp + off);
            op[0] = v0; op[1] = v1;
        } else {
            half8v hv;
#pragma unroll
            for (int j = 0; j < 8; j++) {
                float sv = (float)selfv[j];
                float hnew = 0.9f * dd * (acc[j] + dd * sv) + 0.1f * sv;
                hv[j] = (_Float16)(dd * hnew);
            }
            *reinterpret_cast<half8v*>((_Float16*)outp + off) = hv;
        }
    }
}

// ---------------- launch ----------------

extern "C" void kernel_launch(void* const* d_in, const int* in_sizes, int n_in,
                              void* d_out, int out_size, void* d_ws, size_t ws_size,
                              hipStream_t stream) {
    const float* x     = (const float*)d_in[0];
    const int*   ei    = (const int*)d_in[1];
    const float* W_in  = (const float*)d_in[2];
    const float* b_in  = (const float*)d_in[3];
    const float* W_h   = (const float*)d_in[4];
    const float* b_h   = (const float*)d_in[5];
    const float* W_out = (const float*)d_in[6];
    const float* b_out = (const float*)d_in[7];
    float* out = (float*)d_out;

    const int* srcv = ei;
    const int* dstv = ei + NE;

    char* ws = (char*)d_ws;
    _Float16* h0f  = (_Float16*)ws;                              // NN*32 f16
    _Float16* hs1  = h0f + (size_t)NN * 32;                      // NN*32 f16
    float* dinv    = (float*)(hs1 + (size_t)NN * 32);            // NN
    _Float16* Wf_in  = (_Float16*)(dinv + NN);                   // 256*256
    _Float16* Wf_h   = Wf_in + 256 * 256;                        // 256*256
    _Float16* Wf_out = Wf_h + 256 * 256;                         // 256*32
    int* histT = (int*)(Wf_out + 256 * 32);                      // NBUCK*NCHK
    int* cntb  = histT + (size_t)NBUCK * NCHK;                   // NBUCKP
    int* data  = cntb + NBUCKP;                                  // NBUCKP*CAP
    int* col   = data + (size_t)NBUCKP * CAP;                    // NBUCKP*CAP
    int* begp  = col + (size_t)NBUCKP * CAP;                     // NN
    int* endp  = begp + NN;                                      // NN

    // --- [bucket count | W fragments] ---
    k_count_wfrag<<<NCHK + WFRAG_BLKS, 512, 0, stream>>>(dstv, histT,
                                                         W_in, W_h, W_out,
                                                         Wf_in, Wf_h, Wf_out);
    // --- per-bucket scan ---
    k_scanb<<<NBUCK, 256, 0, stream>>>(histT, cntb);

    // --- [part scatter | fused MLP (inline conversion, h0f only)] ---
    k_part_mlp<<<NCHK + NT64, 512, 0, stream>>>(srcv, dstv, histT, data,
                                                x, Wf_in, Wf_h, Wf_out,
                                                b_in, b_h, b_out, h0f);

    // --- per-bucket counting sort -> CSR + dinv ---
    k_sortb<<<NBUCK, 256, 0, stream>>>(data, cntb, col, begp, endp, dinv);

    // --- APPNP: K = 2 (iter1 folds dinv; iter2 prescaled) ---
    k_appnp<false><<<(NN + 3) / 4, 256, 0, stream>>>(begp, endp, col, dinv, h0f, h0f, hs1);
    k_appnp<true ><<<(NN + 3) / 4, 256, 0, stream>>>(begp, endp, col, dinv, hs1, h0f, out);
}